// Round 3
// baseline (72.765 us; speedup 1.0000x reference)
//
#include <hip/hip_runtime.h>
#include <hip/hip_bf16.h>

#define N 1024
#define BATCH 256
#define NSLAB 16

typedef __attribute__((ext_vector_type(8))) short short8;
typedef __attribute__((ext_vector_type(8))) float f32x8;
typedef __attribute__((ext_vector_type(4))) float f32x4;

static __device__ __forceinline__ ushort bfbits(float f) {
    union { __hip_bfloat16 h; ushort u; } cv;
    cv.h = __float2bfloat16(f);
    return cv.u;
}
static __device__ __forceinline__ float bf2f(ushort u) {
    union { ushort u; __hip_bfloat16 h; } cv;
    cv.u = u;
    return __bfloat162float(cv.h);
}

// ---------------------------------------------------------------------------
// K1: read W [N][N] f32 (row i, col j; j contiguous).
//     Ph[i][j] = bf16(exp(W)), Pl = bf16(residual), plus per-slab column sums
//     psum[slab][j] = sum over 64 rows of exp(W[i][j]).
// grid: 256 blocks = 16 col-groups (64 cols) x 16 row-slabs (64 rows), 256 thr
// (1 block/CU — round-2 used 128 blocks and left half the chip idle)
// ---------------------------------------------------------------------------
__global__ __launch_bounds__(256) void k1_psplit(const float* __restrict__ W,
                                                 float* __restrict__ psum,
                                                 __hip_bfloat16* __restrict__ Ph,
                                                 __hip_bfloat16* __restrict__ Pl) {
    const int t    = threadIdx.x;
    const int jg   = blockIdx.x & 15;   // 16 column groups of 64
    const int slab = blockIdx.x >> 4;   // 16 row slabs of 64
    const int j    = jg * 64 + (t & 63);
    const int rb   = slab * 64 + (t >> 6);   // rows rb + 4*it

    float acc = 0.f;
#pragma unroll 4
    for (int it = 0; it < 16; ++it) {
        const int i   = rb + it * 4;
        const float e = __expf(W[i * N + j]);
        const __hip_bfloat16 h = __float2bfloat16(e);
        Ph[i * N + j] = h;
        Pl[i * N + j] = __float2bfloat16(e - __bfloat162float(h));
        acc += e;
    }
    __shared__ float sm[256];
    sm[t] = acc;
    __syncthreads();
    if (t < 64)
        psum[slab * N + j] = sm[t] + sm[t + 64] + sm[t + 128] + sm[t + 192];
}

// ---------------------------------------------------------------------------
// K3 (fused): out[m][i] = log( sum_j exp(la[m][j]-lcs[j]) * P[i][j] )
// GEMM Q·P^T via split-3 bf16 MFMA (QhPh + QhPl + QlPh; QlPl ~2^-16 dropped).
// Q computed in-register during staging. Register-prefetch pipeline: next
// K-chunk's global loads are issued right after the LDS store so they fly
// across barrier2 + MFMA + barrier1 (no TLP at 1 block/CU — ILP must hide
// L2/L3 latency). exp/split runs on registers BEFORE barrier1.
// Block tile 32(m) x 32(i), BK=64, 4 waves as 2x2 of 16x16 MFMA tiles.
// grid: (256/32)*(1024/32) = 256 blocks, 256 threads.
// LDS rows padded to 72 bf16: both the b128 stage-writes and the fragment
// b128 reads spread uniformly over all 32 banks (8-phase floor, no excess).
// ---------------------------------------------------------------------------
__global__ __launch_bounds__(256) void k3_fused(const float* __restrict__ la,
                                                const float* __restrict__ psum,
                                                const ushort* __restrict__ Ph,
                                                const ushort* __restrict__ Pl,
                                                float* __restrict__ out) {
    __shared__ float  lcs[N];
    __shared__ ushort sQh[32 * 72], sQl[32 * 72], sPh[32 * 72], sPl[32 * 72];

    const int t    = threadIdx.x;
    const int m0   = (blockIdx.x >> 5) * 32;   // 8 m-tiles
    const int i0   = (blockIdx.x & 31) * 32;   // 32 i-tiles
    const int lane = t & 63;
    const int wid  = t >> 6;
    const int wm   = wid >> 1;                 // 0..1
    const int wn   = wid & 1;                  // 0..1

    // lcs[j] = log(colSum[j]) from 16 slab partials; 4 columns per thread
#pragma unroll
    for (int jj = 0; jj < 4; ++jj) {
        const int j = jj * 256 + t;
        float cs = 0.f;
#pragma unroll
        for (int s = 0; s < NSLAB; ++s) cs += psum[s * N + j];
        lcs[j] = __logf(cs);
    }
    __syncthreads();   // lcs ready (barrier1 of iter 0 would be too late:
                       // exp now runs before barrier1)

    // staging ownership: row = t>>3 (0..31), k-offset = (t&7)*8
    const int srow = t >> 3;
    const int skc  = (t & 7) * 8;
    const float*  gla = la + (m0 + srow) * N + skc;
    const ushort* gPh = Ph + (i0 + srow) * N + skc;
    const ushort* gPl = Pl + (i0 + srow) * N + skc;
    const int sdst = srow * 72 + skc;

    // MFMA fragment addresses: lane l holds 8 consecutive k at row l&15,
    // k-base (l>>4)*8 (A and B identical for K-major tiles)
    const int frow = lane & 15;
    const int fkb  = (lane >> 4) * 8;
    const int aoff = (wm * 16 + frow) * 72 + fkb;
    const int boff = (wn * 16 + frow) * 72 + fkb;

    f32x4 acc = {0.f, 0.f, 0.f, 0.f};

    // ---- prefetch chunk 0 ----
    f32x8 vla = *(const f32x8*)(gla);
    short8 vph = *(const short8*)(gPh);
    short8 vpl = *(const short8*)(gPl);

    for (int k0 = 0; k0 < N; k0 += 64) {
        // Q from registers: q = exp(la - lcs), hi/lo bf16 split (pre-barrier)
        short8 qh, ql;
#pragma unroll
        for (int x = 0; x < 8; ++x) {
            const float q  = __expf(vla[x] - lcs[k0 + skc + x]);
            const ushort h = bfbits(q);
            qh[x] = (short)h;
            ql[x] = (short)bfbits(q - bf2f(h));
        }
        __syncthreads();               // previous iter's fragment reads done
        *(short8*)&sQh[sdst] = qh;
        *(short8*)&sQl[sdst] = ql;
        *(short8*)&sPh[sdst] = vph;
        *(short8*)&sPl[sdst] = vpl;
        // ---- issue next chunk's loads; they fly across barrier2+MFMA ----
        if (k0 + 64 < N) {
            vla = *(const f32x8*)(gla + k0 + 64);
            vph = *(const short8*)(gPh + k0 + 64);
            vpl = *(const short8*)(gPl + k0 + 64);
        }
        __syncthreads();               // tile staged
#pragma unroll
        for (int ks = 0; ks < 2; ++ks) {
            const short8 aQh = *(const short8*)&sQh[aoff + ks * 32];
            const short8 aQl = *(const short8*)&sQl[aoff + ks * 32];
            const short8 bPh = *(const short8*)&sPh[boff + ks * 32];
            const short8 bPl = *(const short8*)&sPl[boff + ks * 32];
            acc = __builtin_amdgcn_mfma_f32_16x16x32_bf16(aQh, bPh, acc, 0, 0, 0);
            acc = __builtin_amdgcn_mfma_f32_16x16x32_bf16(aQh, bPl, acc, 0, 0, 0);
            acc = __builtin_amdgcn_mfma_f32_16x16x32_bf16(aQl, bPh, acc, 0, 0, 0);
        }
    }

    // C/D layout (verified m89/m91): col = lane&15, row = (lane>>4)*4 + reg
    const int om = m0 + wm * 16 + (lane >> 4) * 4;
    const int oi = i0 + wn * 16 + (lane & 15);
#pragma unroll
    for (int r = 0; r < 4; ++r)
        out[(om + r) * N + oi] = __logf(acc[r]);
}

// ---------------------------------------------------------------------------
extern "C" void kernel_launch(void* const* d_in, const int* in_sizes, int n_in,
                              void* d_out, int out_size, void* d_ws, size_t ws_size,
                              hipStream_t stream) {
    const float* la = (const float*)d_in[0];   // log_alpha [256][1024]
    const float* W  = (const float*)d_in[1];   // W        [1024][1024]
    float* out = (float*)d_out;                // [256][1024]

    char* ws = (char*)d_ws;
    float* psum        = (float*)ws;                          // 64 KB (16 slabs)
    __hip_bfloat16* Ph = (__hip_bfloat16*)(ws + (64 << 10));  // 2 MB
    __hip_bfloat16* Pl = Ph + (size_t)N * N;                  // 2 MB

    k1_psplit<<<256, 256, 0, stream>>>(W, psum, Ph, Pl);
    k3_fused<<<256, 256, 0, stream>>>(la, psum,
                                      (const ushort*)Ph, (const ushort*)Pl, out);
}

// Round 4
// 68.655 us; speedup vs baseline: 1.0599x; 1.0599x over previous
//
#include <hip/hip_runtime.h>
#include <hip/hip_bf16.h>

#define N 1024
#define BATCH 256
#define LPAD 136   // LDS row stride in bf16 (128 data + 8 pad): 272B = 68 dw = 4 banks mod 32

typedef __attribute__((ext_vector_type(4))) short short4v;
typedef __attribute__((ext_vector_type(8))) short short8;
typedef __attribute__((ext_vector_type(4))) float f32x4;

static __device__ __forceinline__ ushort bfbits(float f) {
    union { __hip_bfloat16 h; ushort u; } cv; cv.h = __float2bfloat16(f); return cv.u;
}
static __device__ __forceinline__ float bf2f(ushort u) {
    union { ushort u; __hip_bfloat16 h; } cv; cv.u = u; return __bfloat162float(cv.h);
}

// ---------------------------------------------------------------------------
// K1: Ph/Pl = bf16 hi/lo split of exp(W); psum[slab][j] = 16-row column sums.
// grid 256 = 64 row-slabs(16) x 4 col-groups(256).  f32x4 loads (16B/lane).
// ---------------------------------------------------------------------------
__global__ __launch_bounds__(256) void k1_psplit(const float* __restrict__ W,
                                                 float* __restrict__ psum,
                                                 ushort* __restrict__ Ph,
                                                 ushort* __restrict__ Pl) {
    const int t = threadIdx.x, lane = t & 63, w = t >> 6;
    const int cg = blockIdx.x & 3, slab = blockIdx.x >> 2;
    const int c = cg * 256 + lane * 4;
    __shared__ f32x4 sm[4][64];
    f32x4 acc = {0.f, 0.f, 0.f, 0.f};
#pragma unroll
    for (int it = 0; it < 4; ++it) {
        const int row = slab * 16 + w * 4 + it;
        const f32x4 v = *(const f32x4*)(W + row * N + c);
        short4v ph, pl;
        f32x4 e;
#pragma unroll
        for (int x = 0; x < 4; ++x) {
            e[x] = __expf(v[x]);
            const ushort h = bfbits(e[x]);
            ph[x] = (short)h;
            pl[x] = (short)bfbits(e[x] - bf2f(h));
        }
        *(short4v*)(Ph + row * N + c) = ph;
        *(short4v*)(Pl + row * N + c) = pl;
        acc += e;
    }
    sm[w][lane] = acc;
    __syncthreads();
    if (t < 64)
        *(f32x4*)(psum + slab * N + c) =
            sm[0][lane] + sm[1][lane] + sm[2][lane] + sm[3][lane];
}

// ---------------------------------------------------------------------------
// K2: lcs[j] = log(colsum); Qh/Ql = bf16 hi/lo split of exp(la[m][j]-lcs[j]).
// grid 128 = 16 m-groups(16 rows) x 8 col-groups(128).
// Removes ALL exp/split VALU from k3's critical path (round-3's k3 recomputed
// 8.4M exps at 1 wave/SIMD — serial VALU on the critical path).
// ---------------------------------------------------------------------------
__global__ __launch_bounds__(256) void k2_qsplit(const float* __restrict__ la,
                                                 const float* __restrict__ psum,
                                                 ushort* __restrict__ Qh,
                                                 ushort* __restrict__ Ql) {
    const int t = threadIdx.x;
    const int cg = blockIdx.x & 7, mg = blockIdx.x >> 3;
    const int c0 = cg * 128;
    __shared__ f32x4 smred[8][32];
    __shared__ float lcs[128];

    // colsum over 64 slabs for this 128-col slice
    const int q = t & 31, sg = t >> 5;
    f32x4 a = {0.f, 0.f, 0.f, 0.f};
#pragma unroll
    for (int i = 0; i < 8; ++i)
        a += *(const f32x4*)(psum + (sg * 8 + i) * N + c0 + q * 4);
    smred[sg][q] = a;
    __syncthreads();
    if (t < 32) {
        f32x4 s = {0.f, 0.f, 0.f, 0.f};
#pragma unroll
        for (int g = 0; g < 8; ++g) s += smred[g][t];
#pragma unroll
        for (int x = 0; x < 4; ++x) lcs[t * 4 + x] = __logf(s[x]);
    }
    __syncthreads();

    // Q split: 16 rows x 128 cols, 8 elems/thread
    const int row = mg * 16 + (t >> 4);
    const int cc  = (t & 15) * 8;
    const float* pla = la + row * N + c0 + cc;
    const f32x4 v0 = *(const f32x4*)(pla);
    const f32x4 v1 = *(const f32x4*)(pla + 4);
    short8 qh, ql;
#pragma unroll
    for (int x = 0; x < 8; ++x) {
        const float lv = (x < 4) ? v0[x] : v1[x - 4];
        const float qv = __expf(lv - lcs[cc + x]);
        const ushort h = bfbits(qv);
        qh[x] = (short)h;
        ql[x] = (short)bfbits(qv - bf2f(h));
    }
    *(short8*)(Qh + row * N + c0 + cc) = qh;
    *(short8*)(Ql + row * N + c0 + cc) = ql;
}

// ---------------------------------------------------------------------------
// K3: pure split-3 bf16 GEMM out[m][i] = log( sum_j Q[m][j]*P[i][j] ).
// 256 blocks (8 m-tiles x 32 i-tiles), tile 32x32, 512 threads = 8 waves
// (2 waves/SIMD): 2x2 quadrants x K-split-2 (each group does K=512), then
// LDS reduce + log.  BK=128/iter (8 iters), register-prefetch pipeline.
// Default block->XCD round-robin already makes P-tiles XCD-local (b%8==i%8).
// ---------------------------------------------------------------------------
__global__ __launch_bounds__(512) void k3_mm(const ushort* __restrict__ Qh,
                                             const ushort* __restrict__ Ql,
                                             const ushort* __restrict__ Ph,
                                             const ushort* __restrict__ Pl,
                                             float* __restrict__ out) {
    __shared__ ushort sQh[32 * LPAD], sQl[32 * LPAD];
    __shared__ ushort sPh[32 * LPAD], sPl[32 * LPAD];

    const int t    = threadIdx.x;
    const int lane = t & 63;
    const int wid  = t >> 6;              // 0..7
    const int wm   = (wid >> 1) & 1;      // quadrant row
    const int wn   = wid & 1;             // quadrant col
    const int g    = wid >> 2;            // K-split group 0/1
    const int m0   = (blockIdx.x >> 5) * 32;
    const int i0   = (blockIdx.x & 31) * 32;

    // staging: 512 thr x 16B per array covers 32 rows x 128 cols bf16
    const int srow = t >> 4;              // 0..31
    const int skc  = (t & 15) * 8;        // 0..120
    const ushort* gQh = Qh + (m0 + srow) * N + skc;
    const ushort* gQl = Ql + (m0 + srow) * N + skc;
    const ushort* gPh = Ph + (i0 + srow) * N + skc;
    const ushort* gPl = Pl + (i0 + srow) * N + skc;
    const int sdst = srow * LPAD + skc;

    // fragments: lane holds row l&15, 8 consecutive k at base (l>>4)*8
    const int aoff = (wm * 16 + (lane & 15)) * LPAD + g * 64 + (lane >> 4) * 8;
    const int boff = (wn * 16 + (lane & 15)) * LPAD + g * 64 + (lane >> 4) * 8;

    f32x4 acc = {0.f, 0.f, 0.f, 0.f};

    short8 vqh = *(const short8*)(gQh);
    short8 vql = *(const short8*)(gQl);
    short8 vph = *(const short8*)(gPh);
    short8 vpl = *(const short8*)(gPl);

    for (int k0 = 0; k0 < N; k0 += 128) {
        __syncthreads();                       // prev iter's frag reads done
        *(short8*)&sQh[sdst] = vqh;
        *(short8*)&sQl[sdst] = vql;
        *(short8*)&sPh[sdst] = vph;
        *(short8*)&sPl[sdst] = vpl;
        if (k0 + 128 < N) {                    // prefetch flies across barrier+MFMA
            vqh = *(const short8*)(gQh + k0 + 128);
            vql = *(const short8*)(gQl + k0 + 128);
            vph = *(const short8*)(gPh + k0 + 128);
            vpl = *(const short8*)(gPl + k0 + 128);
        }
        __syncthreads();                       // tile staged
#pragma unroll
        for (int ks = 0; ks < 2; ++ks) {
            const short8 aQh = *(const short8*)&sQh[aoff + ks * 32];
            const short8 aQl = *(const short8*)&sQl[aoff + ks * 32];
            const short8 bPh = *(const short8*)&sPh[boff + ks * 32];
            const short8 bPl = *(const short8*)&sPl[boff + ks * 32];
            acc = __builtin_amdgcn_mfma_f32_16x16x32_bf16(aQh, bPh, acc, 0, 0, 0);
            acc = __builtin_amdgcn_mfma_f32_16x16x32_bf16(aQh, bPl, acc, 0, 0, 0);
            acc = __builtin_amdgcn_mfma_f32_16x16x32_bf16(aQl, bPh, acc, 0, 0, 0);
        }
    }

    // K-split reduce (reuse sQh as f32x4 scratch: 8*64*16B = 8KB <= 8704B)
    __syncthreads();
    f32x4* red = (f32x4*)sQh;
    red[wid * 64 + lane] = acc;
    __syncthreads();
    if (wid < 4) {
        const f32x4 s = red[wid * 64 + lane] + red[(wid + 4) * 64 + lane];
        const int om = m0 + wm * 16 + (lane >> 4) * 4;
        const int oi = i0 + wn * 16 + (lane & 15);
#pragma unroll
        for (int r = 0; r < 4; ++r)
            out[(om + r) * N + oi] = __logf(s[r]);
    }
}

// ---------------------------------------------------------------------------
extern "C" void kernel_launch(void* const* d_in, const int* in_sizes, int n_in,
                              void* d_out, int out_size, void* d_ws, size_t ws_size,
                              hipStream_t stream) {
    const float* la = (const float*)d_in[0];   // [256][1024]
    const float* W  = (const float*)d_in[1];   // [1024][1024]
    float* out = (float*)d_out;                // [256][1024]

    char* ws = (char*)d_ws;
    float*  psum = (float*)ws;                             // 256 KB (64 slabs)
    ushort* Ph   = (ushort*)(ws + (256 << 10));            // 2 MB
    ushort* Pl   = Ph + (size_t)N * N;                     // 2 MB
    ushort* Qh   = Pl + (size_t)N * N;                     // 512 KB
    ushort* Ql   = Qh + (size_t)BATCH * N;                 // 512 KB

    k1_psplit<<<256, 256, 0, stream>>>(W, psum, Ph, Pl);
    k2_qsplit<<<128, 256, 0, stream>>>(la, psum, Qh, Ql);
    k3_mm<<<256, 512, 0, stream>>>(Qh, Ql, Ph, Pl, out);
}